// Round 8
// baseline (144.897 us; speedup 1.0000x reference)
//
#include <hip/hip_runtime.h>

typedef __bf16 bf16_t;
typedef __bf16 bf16x8 __attribute__((ext_vector_type(8)));
typedef __bf16 bf16x4 __attribute__((ext_vector_type(4)));
typedef float  f32x4  __attribute__((ext_vector_type(4)));

static constexpr int B_   = 2;
static constexpr int H_   = 48;
static constexpr int W_   = 48;
static constexpr int C_   = 512;
static constexpr int NH_  = 8;
static constexpr int HD_  = 64;
static constexpr int KW_  = 7;
static constexpr int ROWS_ = B_ * H_ * W_;    // 4608
static constexpr int QKVN_ = 3 * C_;          // 1536

// async global->LDS, 16B per lane; LDS dest = wave-uniform base + lane*16
#define GLDS16(g, l) __builtin_amdgcn_global_load_lds(                       \
    (const __attribute__((address_space(1))) void*)(g),                      \
    (__attribute__((address_space(3))) void*)(l), 16, 0, 0)

// fp32 -> bf16 pre-convert for x, qkv_w, proj_w
__global__ __launch_bounds__(256)
void convert_kernel(const float* __restrict__ x,  const float* __restrict__ qw,
                    const float* __restrict__ pw,
                    bf16_t* __restrict__ xb, bf16_t* __restrict__ qwb,
                    bf16_t* __restrict__ pwb)
{
    constexpr int NX = ROWS_ * C_;
    constexpr int NQ = QKVN_ * C_;
    constexpr int NP = C_ * C_;
    const int idx = (blockIdx.x * 256 + threadIdx.x) * 4;
    if (idx >= NX + NQ + NP) return;
    const float* src; bf16_t* dst; int off;
    if (idx < NX)           { src = x;  dst = xb;  off = idx; }
    else if (idx < NX + NQ) { src = qw; dst = qwb; off = idx - NX; }
    else                    { src = pw; dst = pwb; off = idx - NX - NQ; }
    const float4 v = *reinterpret_cast<const float4*>(src + off);
    bf16x4 o;
    o[0] = (bf16_t)v.x; o[1] = (bf16_t)v.y; o[2] = (bf16_t)v.z; o[3] = (bf16_t)v.w;
    *reinterpret_cast<bf16x4*>(dst + off) = o;
}

// C[m][n] = (sum_k A[m][k]*Wt[n][k] + bias[n]) * (n < scale_nlim ? scale : 1)
template<int BM, int BN, int WMT, int WNT, int KTILE, typename OutT>
__global__ __launch_bounds__(256)
void gemm_bt(const bf16_t* __restrict__ A, const bf16_t* __restrict__ Wt,
             const float* __restrict__ bias, OutT* __restrict__ C,
             int M, int N, int K, float scale, int scale_nlim)
{
    constexpr int WCOLS = BN / (WNT * 16);
    constexpr int CPR   = KTILE / 8;
    constexpr int RPI   = 64 / CPR;
    constexpr int KSN   = KTILE / 32;
    __shared__ bf16_t Al[BM * KTILE];
    __shared__ bf16_t Bl[BN * KTILE];

    const int tid  = threadIdx.x;
    const int wave = tid >> 6;
    const int lane = tid & 63;
    const int bm = blockIdx.y * BM;
    const int bn = blockIdx.x * BN;
    const int wm = (wave / WCOLS) * (WMT * 16);
    const int wn = (wave % WCOLS) * (WNT * 16);
    const int n15 = lane & 15, q4 = lane >> 4, x7 = lane & 7;
    const int srow = lane / CPR;
    const int schunk = lane % CPR;

    f32x4 acc[WMT][WNT] = {};

    for (int k0 = 0; k0 < K; k0 += KTILE) {
        __syncthreads();
        #pragma unroll
        for (int i = wave; i < BM / RPI; i += 4) {
            const int row = i * RPI + srow;
            const int cg = (schunk & ~7) | ((schunk & 7) ^ (row & 7));
            GLDS16(A + (size_t)(bm + row) * K + k0 + cg * 8, Al + i * 512);
        }
        #pragma unroll
        for (int i = wave; i < BN / RPI; i += 4) {
            const int row = i * RPI + srow;
            const int cg = (schunk & ~7) | ((schunk & 7) ^ (row & 7));
            GLDS16(Wt + (size_t)(bn + row) * K + k0 + cg * 8, Bl + i * 512);
        }
        __syncthreads();

        #pragma unroll
        for (int ks = 0; ks < KSN; ++ks) {
            const int g = ks * 4 + q4;
            const int cl = (g & ~7) | ((g & 7) ^ x7);
            bf16x8 a[WMT], b[WNT];
            #pragma unroll
            for (int it = 0; it < WMT; ++it)
                a[it] = *reinterpret_cast<const bf16x8*>(
                    Al + (wm + it * 16 + n15) * KTILE + cl * 8);
            #pragma unroll
            for (int jt = 0; jt < WNT; ++jt)
                b[jt] = *reinterpret_cast<const bf16x8*>(
                    Bl + (wn + jt * 16 + n15) * KTILE + cl * 8);
            #pragma unroll
            for (int it = 0; it < WMT; ++it)
                #pragma unroll
                for (int jt = 0; jt < WNT; ++jt)
                    acc[it][jt] = __builtin_amdgcn_mfma_f32_16x16x32_bf16(
                        a[it], b[jt], acc[it][jt], 0, 0, 0);
        }
    }

    #pragma unroll
    for (int jt = 0; jt < WNT; ++jt) {
        const int col = bn + wn + jt * 16 + n15;
        const float bv = bias[col];
        const float sc = (col < scale_nlim) ? scale : 1.0f;
        #pragma unroll
        for (int it = 0; it < WMT; ++it) {
            const int row0 = bm + wm + it * 16 + q4 * 4;
            #pragma unroll
            for (int r = 0; r < 4; ++r)
                C[(size_t)(row0 + r) * N + col] = (OutT)((acc[it][jt][r] + bv) * sc);
        }
    }
}

// ---------------- MFMA neighborhood attention (identical to R7) ----------------
static constexpr int WROW = 224;
static constexpr int PST  = 232;
static constexpr int R1B  = 64 * PST * 2;    // 29696: P region (Kl aliases)
static constexpr int R2B  = WROW * 64 * 2;   // 28672: Vl

__global__ __launch_bounds__(256)
void attn_mfma_kernel(const bf16_t* __restrict__ qkv, bf16_t* __restrict__ attn_out)
{
    int bid = blockIdx.x;
    const int h  = bid & 7;   bid >>= 3;
    const int tj = bid % 6;   bid /= 6;
    const int ti = bid % 6;   bid /= 6;
    const int b  = bid;

    const int tid = threadIdx.x;
    const int wave = tid >> 6;
    const int lane = tid & 63;
    const int n15 = lane & 15, q4 = lane >> 4, x7 = lane & 7;

    const int gi0 = ti * 8, gj0 = tj * 8;
    const int si0 = min(max(gi0 - 3, 0), H_ - 14);
    const int sj0 = min(max(gj0 - 3, 0), W_ - 14);

    __shared__ char smem[R1B + R2B];
    bf16_t* Kl = (bf16_t*)smem;
    bf16_t* P  = (bf16_t*)smem;
    bf16_t* Vl = (bf16_t*)(smem + R1B);

    for (int i = wave; i < WROW / 8; i += 4) {
        const int row = i * 8 + (lane >> 3);
        const int wr = row >> 4;
        const int wc = min(row & 15, 13);
        const int gp = (b * H_ + si0 + wr) * W_ + sj0 + wc;
        const bf16_t* gbase = qkv + (size_t)gp * QKVN_ + h * HD_;
        const int cgk = (lane & 7) ^ (row & 7);
        GLDS16(gbase + C_ + cgk * 8, Kl + i * 512);
        const int cgv = (lane & 7) ^ ((row + (row >> 3)) & 7);
        GLDS16(gbase + 2 * C_ + cgv * 8, Vl + i * 512);
    }

    const int pixq = wave * 16 + n15;
    const int gpq = (b * H_ + gi0 + (pixq >> 3)) * W_ + gj0 + (pixq & 7);
    bf16x8 aq[2];
    #pragma unroll
    for (int ks = 0; ks < 2; ++ks)
        aq[ks] = *reinterpret_cast<const bf16x8*>(
            qkv + (size_t)gpq * QKVN_ + h * HD_ + ks * 32 + q4 * 8);

    __syncthreads();

    f32x4 S[14] = {};
    #pragma unroll
    for (int j = 0; j < 14; ++j) {
        #pragma unroll
        for (int ks = 0; ks < 2; ++ks) {
            const int cl = (ks * 4 + q4) ^ x7;
            const bf16x8 bk = *reinterpret_cast<const bf16x8*>(
                Kl + (j * 16 + n15) * 64 + cl * 8);
            S[j] = __builtin_amdgcn_mfma_f32_16x16x32_bf16(aq[ks], bk, S[j], 0, 0, 0);
        }
    }

    int ri[4], cj[4];
    #pragma unroll
    for (int r = 0; r < 4; ++r) {
        const int pix = wave * 16 + q4 * 4 + r;
        const int gi = gi0 + (pix >> 3), gj = gj0 + (pix & 7);
        ri[r] = min(max(gi - 3, 0), H_ - KW_) - si0;
        cj[r] = min(max(gj - 3, 0), W_ - KW_) - sj0;
    }
    #pragma unroll
    for (int j = 0; j < 14; ++j)
        #pragma unroll
        for (int r = 0; r < 4; ++r) {
            const bool valid = ((unsigned)(j - ri[r]) < 7u) &&
                               ((unsigned)(n15 - cj[r]) < 7u);
            S[j][r] = valid ? S[j][r] : -1e30f;
        }

    #pragma unroll
    for (int j = 0; j < 14; ++j)
        #pragma unroll
        for (int r = 0; r < 4; ++r)
            S[j][r] = __expf(S[j][r]);
    float rinv[4];
    #pragma unroll
    for (int r = 0; r < 4; ++r) {
        float s = S[0][r];
        #pragma unroll
        for (int j = 1; j < 14; ++j) s += S[j][r];
        #pragma unroll
        for (int off = 1; off < 16; off <<= 1) s += __shfl_xor(s, off);
        rinv[r] = 1.0f / s;
    }

    __syncthreads();

    #pragma unroll
    for (int j = 0; j < 14; ++j)
        #pragma unroll
        for (int r = 0; r < 4; ++r)
            P[(wave * 16 + q4 * 4 + r) * PST + j * 16 + n15] =
                (bf16_t)(S[j][r] * rinv[r]);

    __syncthreads();

    const int Xv   = wave * 2 + (n15 >> 3);
    const int dlow = n15 & 7;
    f32x4 O[4] = {};
    #pragma unroll
    for (int ks = 0; ks < 7; ++ks) {
        bf16x8 av;
        #pragma unroll
        for (int u = 0; u < 8; ++u) {
            const int w = ks * 32 + q4 * 8 + u;
            const int slot = Xv ^ ((w + (w >> 3)) & 7);
            av[u] = Vl[w * 64 + slot * 8 + dlow];
        }
        #pragma unroll
        for (int j2 = 0; j2 < 4; ++j2) {
            const bf16x8 bp = *reinterpret_cast<const bf16x8*>(
                P + (j2 * 16 + n15) * PST + ks * 32 + q4 * 8);
            O[j2] = __builtin_amdgcn_mfma_f32_16x16x32_bf16(av, bp, O[j2], 0, 0, 0);
        }
    }

    #pragma unroll
    for (int j2 = 0; j2 < 4; ++j2) {
        const int pix = j2 * 16 + n15;
        const int grow = (b * H_ + gi0 + (pix >> 3)) * W_ + gj0 + (pix & 7);
        const int d0 = wave * 16 + q4 * 4;
        bf16x4 o;
        #pragma unroll
        for (int r = 0; r < 4; ++r) o[r] = (bf16_t)(O[j2][r]);
        *reinterpret_cast<bf16x4*>(attn_out + (size_t)grow * C_ + h * HD_ + d0) = o;
    }
}

extern "C" void kernel_launch(void* const* d_in, const int* in_sizes, int n_in,
                              void* d_out, int out_size, void* d_ws, size_t ws_size,
                              hipStream_t stream)
{
    const float* x      = (const float*)d_in[0];
    const float* qkv_w  = (const float*)d_in[1];
    const float* qkv_b  = (const float*)d_in[2];
    const float* proj_w = (const float*)d_in[3];
    const float* proj_b = (const float*)d_in[4];
    float* out = (float*)d_out;

    char* w = (char*)d_ws;
    bf16_t* xb    = (bf16_t*)w;  w += (size_t)ROWS_ * C_ * 2;
    bf16_t* qwb   = (bf16_t*)w;  w += (size_t)QKVN_ * C_ * 2;
    bf16_t* pwb   = (bf16_t*)w;  w += (size_t)C_ * C_ * 2;
    bf16_t* qkvb  = (bf16_t*)w;  w += (size_t)ROWS_ * QKVN_ * 2;
    bf16_t* attnb = (bf16_t*)w;

    // DIAGNOSTIC ROUND: every kernel launched twice (all are idempotent pure
    // functions of their inputs). 2*R7_dur - R8_dur estimates the fixed floor
    // in the timed window. Final config will revert to single launches.
    constexpr int TOT4 = (ROWS_ * C_ + QKVN_ * C_ + C_ * C_) / 4;
    convert_kernel<<<(TOT4 + 255) / 256, 256, 0, stream>>>(x, qkv_w, proj_w, xb, qwb, pwb);
    convert_kernel<<<(TOT4 + 255) / 256, 256, 0, stream>>>(x, qkv_w, proj_w, xb, qwb, pwb);

    gemm_bt<128, 64, 4, 2, 64, bf16_t><<<dim3(QKVN_ / 64, ROWS_ / 128), 256, 0, stream>>>(
        xb, qwb, qkv_b, qkvb, ROWS_, QKVN_, C_, 0.125f, C_);
    gemm_bt<128, 64, 4, 2, 64, bf16_t><<<dim3(QKVN_ / 64, ROWS_ / 128), 256, 0, stream>>>(
        xb, qwb, qkv_b, qkvb, ROWS_, QKVN_, C_, 0.125f, C_);

    attn_mfma_kernel<<<dim3(B_ * 6 * 6 * NH_), 256, 0, stream>>>(qkvb, attnb);
    attn_mfma_kernel<<<dim3(B_ * 6 * 6 * NH_), 256, 0, stream>>>(qkvb, attnb);

    gemm_bt<64, 64, 2, 2, 64, float><<<dim3(C_ / 64, ROWS_ / 64), 256, 0, stream>>>(
        attnb, pwb, proj_b, out, ROWS_, C_, C_, 1.0f, 0);
    gemm_bt<64, 64, 2, 2, 64, float><<<dim3(C_ / 64, ROWS_ / 64), 256, 0, stream>>>(
        attnb, pwb, proj_b, out, ROWS_, C_, C_, 1.0f, 0);
}

// Round 9
// 117.084 us; speedup vs baseline: 1.2376x; 1.2376x over previous
//
#include <hip/hip_runtime.h>

typedef __bf16 bf16_t;
typedef __bf16 bf16x8 __attribute__((ext_vector_type(8)));
typedef __bf16 bf16x4 __attribute__((ext_vector_type(4)));
typedef float  f32x4  __attribute__((ext_vector_type(4)));

static constexpr int B_   = 2;
static constexpr int H_   = 48;
static constexpr int W_   = 48;
static constexpr int C_   = 512;
static constexpr int NH_  = 8;
static constexpr int HD_  = 64;
static constexpr int KW_  = 7;
static constexpr int ROWS_ = B_ * H_ * W_;    // 4608
static constexpr int QKVN_ = 3 * C_;          // 1536

// async global->LDS, 16B per lane; LDS dest = wave-uniform base + lane*16
#define GLDS16(g, l) __builtin_amdgcn_global_load_lds(                       \
    (const __attribute__((address_space(1))) void*)(g),                      \
    (__attribute__((address_space(3))) void*)(l), 16, 0, 0)

// fp32 -> bf16 pre-convert, weights only (x is converted inside gemm1)
__global__ __launch_bounds__(256)
void convert_w_kernel(const float* __restrict__ qw, const float* __restrict__ pw,
                      bf16_t* __restrict__ qwb, bf16_t* __restrict__ pwb)
{
    constexpr int NQ = QKVN_ * C_;   // 786432
    constexpr int NP = C_ * C_;      // 262144
    const int idx = (blockIdx.x * 256 + threadIdx.x) * 4;
    if (idx >= NQ + NP) return;
    const float* src; bf16_t* dst; int off;
    if (idx < NQ) { src = qw; dst = qwb; off = idx; }
    else          { src = pw; dst = pwb; off = idx - NQ; }
    const float4 v = *reinterpret_cast<const float4*>(src + off);
    bf16x4 o;
    o[0] = (bf16_t)v.x; o[1] = (bf16_t)v.y; o[2] = (bf16_t)v.z; o[3] = (bf16_t)v.w;
    *reinterpret_cast<bf16x4*>(dst + off) = o;
}

// gemm1 fused: A fp32 (x), converted during staging with register prefetch
// pipeline; B bf16 via GLDS16. 128x128 tile, KTILE=64, 4 waves 2x2.
// qkv = x @ qkv_w.T + qkv_b, q-part (col<512) scaled by 0.125.
__global__ __launch_bounds__(256)
void gemm1_fused(const float* __restrict__ A, const bf16_t* __restrict__ Wt,
                 const float* __restrict__ bias, bf16_t* __restrict__ C,
                 int M, int N, int K, float scale, int scale_nlim)
{
    constexpr int BM = 128, BN = 128;
    __shared__ bf16_t Al[BM * 64];
    __shared__ bf16_t Bl[BN * 64];

    const int tid  = threadIdx.x;
    const int wave = tid >> 6;
    const int lane = tid & 63;
    const int bm = blockIdx.y * BM;
    const int bn = blockIdx.x * BN;
    const int wm = (wave >> 1) * 64;
    const int wn = (wave & 1) * 64;
    const int n15 = lane & 15, q4 = lane >> 4, x7 = lane & 7;

    // A staging: thread t -> row t>>1, half (t&1): chunks h*4..h*4+3 (32B fp32 each)
    const int arow = tid >> 1;
    const int ah   = (tid & 1) * 4;
    const float* Ag = A + (size_t)(bm + arow) * K;
    // B staging (async DMA)
    const int srow = lane >> 3, schunk = lane & 7;

    f32x4 acc[4][4] = {};
    float4 f[8];

    // preload A tile 0 into registers
    #pragma unroll
    for (int ci = 0; ci < 4; ++ci) {
        f[2 * ci]     = *reinterpret_cast<const float4*>(Ag + (ah + ci) * 8);
        f[2 * ci + 1] = *reinterpret_cast<const float4*>(Ag + (ah + ci) * 8 + 4);
    }

    for (int k0 = 0; k0 < K; k0 += 64) {
        __syncthreads();   // previous iter's LDS reads complete
        // convert + write A tile (consumes f)
        #pragma unroll
        for (int ci = 0; ci < 4; ++ci) {
            bf16x8 o;
            o[0] = (bf16_t)f[2 * ci].x;     o[1] = (bf16_t)f[2 * ci].y;
            o[2] = (bf16_t)f[2 * ci].z;     o[3] = (bf16_t)f[2 * ci].w;
            o[4] = (bf16_t)f[2 * ci + 1].x; o[5] = (bf16_t)f[2 * ci + 1].y;
            o[6] = (bf16_t)f[2 * ci + 1].z; o[7] = (bf16_t)f[2 * ci + 1].w;
            const int slot = (ah + ci) ^ (arow & 7);
            *reinterpret_cast<bf16x8*>(Al + arow * 64 + slot * 8) = o;
        }
        // B tile via async DMA
        #pragma unroll
        for (int i = wave; i < 16; i += 4) {
            const int row = i * 8 + srow;
            const int cg = schunk ^ (row & 7);
            GLDS16(Wt + (size_t)(bn + row) * K + k0 + cg * 8, Bl + i * 512);
        }
        __syncthreads();   // drain lgkm (A writes) + vm (B DMA)

        // prefetch next A tile into registers — overlaps the MFMAs below
        if (k0 + 64 < K) {
            #pragma unroll
            for (int ci = 0; ci < 4; ++ci) {
                f[2 * ci]     = *reinterpret_cast<const float4*>(Ag + k0 + 64 + (ah + ci) * 8);
                f[2 * ci + 1] = *reinterpret_cast<const float4*>(Ag + k0 + 64 + (ah + ci) * 8 + 4);
            }
        }

        #pragma unroll
        for (int ks = 0; ks < 2; ++ks) {
            const int cl = (ks * 4 + q4) ^ x7;
            bf16x8 a[4], b[4];
            #pragma unroll
            for (int it = 0; it < 4; ++it)
                a[it] = *reinterpret_cast<const bf16x8*>(
                    Al + (wm + it * 16 + n15) * 64 + cl * 8);
            #pragma unroll
            for (int jt = 0; jt < 4; ++jt)
                b[jt] = *reinterpret_cast<const bf16x8*>(
                    Bl + (wn + jt * 16 + n15) * 64 + cl * 8);
            #pragma unroll
            for (int it = 0; it < 4; ++it)
                #pragma unroll
                for (int jt = 0; jt < 4; ++jt)
                    acc[it][jt] = __builtin_amdgcn_mfma_f32_16x16x32_bf16(
                        a[it], b[jt], acc[it][jt], 0, 0, 0);
        }
    }

    #pragma unroll
    for (int jt = 0; jt < 4; ++jt) {
        const int col = bn + wn + jt * 16 + n15;
        const float bv = bias[col];
        const float sc = (col < scale_nlim) ? scale : 1.0f;
        #pragma unroll
        for (int it = 0; it < 4; ++it) {
            const int row0 = bm + wm + it * 16 + q4 * 4;
            #pragma unroll
            for (int r = 0; r < 4; ++r)
                C[(size_t)(row0 + r) * N + col] = (bf16_t)((acc[it][jt][r] + bv) * sc);
        }
    }
}

// generic bf16 GEMM (used for proj): KTILE=64
template<int BM, int BN, int WMT, int WNT, typename OutT>
__global__ __launch_bounds__(256)
void gemm_bt(const bf16_t* __restrict__ A, const bf16_t* __restrict__ Wt,
             const float* __restrict__ bias, OutT* __restrict__ C,
             int M, int N, int K, float scale, int scale_nlim)
{
    constexpr int WCOLS = BN / (WNT * 16);
    __shared__ bf16_t Al[BM * 64];
    __shared__ bf16_t Bl[BN * 64];

    const int tid  = threadIdx.x;
    const int wave = tid >> 6;
    const int lane = tid & 63;
    const int bm = blockIdx.y * BM;
    const int bn = blockIdx.x * BN;
    const int wm = (wave / WCOLS) * (WMT * 16);
    const int wn = (wave % WCOLS) * (WNT * 16);
    const int n15 = lane & 15, q4 = lane >> 4, x7 = lane & 7;
    const int srow = lane >> 3, schunk = lane & 7;

    f32x4 acc[WMT][WNT] = {};

    for (int k0 = 0; k0 < K; k0 += 64) {
        __syncthreads();
        #pragma unroll
        for (int i = wave; i < BM / 8; i += 4) {
            const int row = i * 8 + srow;
            const int cg = schunk ^ (row & 7);
            GLDS16(A + (size_t)(bm + row) * K + k0 + cg * 8, Al + i * 512);
        }
        #pragma unroll
        for (int i = wave; i < BN / 8; i += 4) {
            const int row = i * 8 + srow;
            const int cg = schunk ^ (row & 7);
            GLDS16(Wt + (size_t)(bn + row) * K + k0 + cg * 8, Bl + i * 512);
        }
        __syncthreads();

        #pragma unroll
        for (int ks = 0; ks < 2; ++ks) {
            const int cl = (ks * 4 + q4) ^ x7;
            bf16x8 a[WMT], b[WNT];
            #pragma unroll
            for (int it = 0; it < WMT; ++it)
                a[it] = *reinterpret_cast<const bf16x8*>(
                    Al + (wm + it * 16 + n15) * 64 + cl * 8);
            #pragma unroll
            for (int jt = 0; jt < WNT; ++jt)
                b[jt] = *reinterpret_cast<const bf16x8*>(
                    Bl + (wn + jt * 16 + n15) * 64 + cl * 8);
            #pragma unroll
            for (int it = 0; it < WMT; ++it)
                #pragma unroll
                for (int jt = 0; jt < WNT; ++jt)
                    acc[it][jt] = __builtin_amdgcn_mfma_f32_16x16x32_bf16(
                        a[it], b[jt], acc[it][jt], 0, 0, 0);
        }
    }

    #pragma unroll
    for (int jt = 0; jt < WNT; ++jt) {
        const int col = bn + wn + jt * 16 + n15;
        const float bv = bias[col];
        const float sc = (col < scale_nlim) ? scale : 1.0f;
        #pragma unroll
        for (int it = 0; it < WMT; ++it) {
            const int row0 = bm + wm + it * 16 + q4 * 4;
            #pragma unroll
            for (int r = 0; r < 4; ++r)
                C[(size_t)(row0 + r) * N + col] = (OutT)((acc[it][jt][r] + bv) * sc);
        }
    }
}

// ---------------- MFMA neighborhood attention (identical to R7) ----------------
static constexpr int WROW = 224;
static constexpr int PST  = 232;
static constexpr int R1B  = 64 * PST * 2;    // 29696: P region (Kl aliases)
static constexpr int R2B  = WROW * 64 * 2;   // 28672: Vl

__global__ __launch_bounds__(256)
void attn_mfma_kernel(const bf16_t* __restrict__ qkv, bf16_t* __restrict__ attn_out)
{
    int bid = blockIdx.x;
    const int h  = bid & 7;   bid >>= 3;
    const int tj = bid % 6;   bid /= 6;
    const int ti = bid % 6;   bid /= 6;
    const int b  = bid;

    const int tid = threadIdx.x;
    const int wave = tid >> 6;
    const int lane = tid & 63;
    const int n15 = lane & 15, q4 = lane >> 4, x7 = lane & 7;

    const int gi0 = ti * 8, gj0 = tj * 8;
    const int si0 = min(max(gi0 - 3, 0), H_ - 14);
    const int sj0 = min(max(gj0 - 3, 0), W_ - 14);

    __shared__ char smem[R1B + R2B];
    bf16_t* Kl = (bf16_t*)smem;
    bf16_t* P  = (bf16_t*)smem;
    bf16_t* Vl = (bf16_t*)(smem + R1B);

    for (int i = wave; i < WROW / 8; i += 4) {
        const int row = i * 8 + (lane >> 3);
        const int wr = row >> 4;
        const int wc = min(row & 15, 13);
        const int gp = (b * H_ + si0 + wr) * W_ + sj0 + wc;
        const bf16_t* gbase = qkv + (size_t)gp * QKVN_ + h * HD_;
        const int cgk = (lane & 7) ^ (row & 7);
        GLDS16(gbase + C_ + cgk * 8, Kl + i * 512);
        const int cgv = (lane & 7) ^ ((row + (row >> 3)) & 7);
        GLDS16(gbase + 2 * C_ + cgv * 8, Vl + i * 512);
    }

    const int pixq = wave * 16 + n15;
    const int gpq = (b * H_ + gi0 + (pixq >> 3)) * W_ + gj0 + (pixq & 7);
    bf16x8 aq[2];
    #pragma unroll
    for (int ks = 0; ks < 2; ++ks)
        aq[ks] = *reinterpret_cast<const bf16x8*>(
            qkv + (size_t)gpq * QKVN_ + h * HD_ + ks * 32 + q4 * 8);

    __syncthreads();

    f32x4 S[14] = {};
    #pragma unroll
    for (int j = 0; j < 14; ++j) {
        #pragma unroll
        for (int ks = 0; ks < 2; ++ks) {
            const int cl = (ks * 4 + q4) ^ x7;
            const bf16x8 bk = *reinterpret_cast<const bf16x8*>(
                Kl + (j * 16 + n15) * 64 + cl * 8);
            S[j] = __builtin_amdgcn_mfma_f32_16x16x32_bf16(aq[ks], bk, S[j], 0, 0, 0);
        }
    }

    int ri[4], cj[4];
    #pragma unroll
    for (int r = 0; r < 4; ++r) {
        const int pix = wave * 16 + q4 * 4 + r;
        const int gi = gi0 + (pix >> 3), gj = gj0 + (pix & 7);
        ri[r] = min(max(gi - 3, 0), H_ - KW_) - si0;
        cj[r] = min(max(gj - 3, 0), W_ - KW_) - sj0;
    }
    #pragma unroll
    for (int j = 0; j < 14; ++j)
        #pragma unroll
        for (int r = 0; r < 4; ++r) {
            const bool valid = ((unsigned)(j - ri[r]) < 7u) &&
                               ((unsigned)(n15 - cj[r]) < 7u);
            S[j][r] = valid ? S[j][r] : -1e30f;
        }

    #pragma unroll
    for (int j = 0; j < 14; ++j)
        #pragma unroll
        for (int r = 0; r < 4; ++r)
            S[j][r] = __expf(S[j][r]);
    float rinv[4];
    #pragma unroll
    for (int r = 0; r < 4; ++r) {
        float s = S[0][r];
        #pragma unroll
        for (int j = 1; j < 14; ++j) s += S[j][r];
        #pragma unroll
        for (int off = 1; off < 16; off <<= 1) s += __shfl_xor(s, off);
        rinv[r] = 1.0f / s;
    }

    __syncthreads();

    #pragma unroll
    for (int j = 0; j < 14; ++j)
        #pragma unroll
        for (int r = 0; r < 4; ++r)
            P[(wave * 16 + q4 * 4 + r) * PST + j * 16 + n15] =
                (bf16_t)(S[j][r] * rinv[r]);

    __syncthreads();

    const int Xv   = wave * 2 + (n15 >> 3);
    const int dlow = n15 & 7;
    f32x4 O[4] = {};
    #pragma unroll
    for (int ks = 0; ks < 7; ++ks) {
        bf16x8 av;
        #pragma unroll
        for (int u = 0; u < 8; ++u) {
            const int w = ks * 32 + q4 * 8 + u;
            const int slot = Xv ^ ((w + (w >> 3)) & 7);
            av[u] = Vl[w * 64 + slot * 8 + dlow];
        }
        #pragma unroll
        for (int j2 = 0; j2 < 4; ++j2) {
            const bf16x8 bp = *reinterpret_cast<const bf16x8*>(
                P + (j2 * 16 + n15) * PST + ks * 32 + q4 * 8);
            O[j2] = __builtin_amdgcn_mfma_f32_16x16x32_bf16(av, bp, O[j2], 0, 0, 0);
        }
    }

    #pragma unroll
    for (int j2 = 0; j2 < 4; ++j2) {
        const int pix = j2 * 16 + n15;
        const int grow = (b * H_ + gi0 + (pix >> 3)) * W_ + gj0 + (pix & 7);
        const int d0 = wave * 16 + q4 * 4;
        bf16x4 o;
        #pragma unroll
        for (int r = 0; r < 4; ++r) o[r] = (bf16_t)(O[j2][r]);
        *reinterpret_cast<bf16x4*>(attn_out + (size_t)grow * C_ + h * HD_ + d0) = o;
    }
}

extern "C" void kernel_launch(void* const* d_in, const int* in_sizes, int n_in,
                              void* d_out, int out_size, void* d_ws, size_t ws_size,
                              hipStream_t stream)
{
    const float* x      = (const float*)d_in[0];
    const float* qkv_w  = (const float*)d_in[1];
    const float* qkv_b  = (const float*)d_in[2];
    const float* proj_w = (const float*)d_in[3];
    const float* proj_b = (const float*)d_in[4];
    float* out = (float*)d_out;

    char* w = (char*)d_ws;
    bf16_t* qwb   = (bf16_t*)w;  w += (size_t)QKVN_ * C_ * 2;
    bf16_t* pwb   = (bf16_t*)w;  w += (size_t)C_ * C_ * 2;
    bf16_t* qkvb  = (bf16_t*)w;  w += (size_t)ROWS_ * QKVN_ * 2;
    bf16_t* attnb = (bf16_t*)w;

    // 0) fp32 -> bf16 casts, weights only (x converted inside gemm1)
    constexpr int TOTW4 = (QKVN_ * C_ + C_ * C_) / 4;
    convert_w_kernel<<<(TOTW4 + 255) / 256, 256, 0, stream>>>(qkv_w, proj_w, qwb, pwb);

    // 1) QKV = x @ qkv_w.T + qkv_b ; fused fp32-A staging, 128x128 -> 432 blocks
    gemm1_fused<<<dim3(QKVN_ / 128, ROWS_ / 128), 256, 0, stream>>>(
        x, qwb, qkv_b, qkvb, ROWS_, QKVN_, C_, 0.125f, C_);

    // 2) neighborhood attention (MFMA), 576 blocks
    attn_mfma_kernel<<<dim3(B_ * 6 * 6 * NH_), 256, 0, stream>>>(qkvb, attnb);

    // 3) out = attn @ proj_w.T + proj_b.  64x64 -> 576 blocks
    gemm_bt<64, 64, 2, 2, float><<<dim3(C_ / 64, ROWS_ / 64), 256, 0, stream>>>(
        attnb, pwb, proj_b, out, ROWS_, C_, C_, 1.0f, 0);
}

// Round 10
// 109.537 us; speedup vs baseline: 1.3228x; 1.0689x over previous
//
#include <hip/hip_runtime.h>

typedef __bf16 bf16_t;
typedef __bf16 bf16x8 __attribute__((ext_vector_type(8)));
typedef __bf16 bf16x4 __attribute__((ext_vector_type(4)));
typedef float  f32x4  __attribute__((ext_vector_type(4)));

static constexpr int B_   = 2;
static constexpr int H_   = 48;
static constexpr int W_   = 48;
static constexpr int C_   = 512;
static constexpr int NH_  = 8;
static constexpr int HD_  = 64;
static constexpr int KW_  = 7;
static constexpr int ROWS_ = B_ * H_ * W_;    // 4608
static constexpr int QKVN_ = 3 * C_;          // 1536

// async global->LDS, 16B per lane; LDS dest = wave-uniform base + lane*16
#define GLDS16(g, l) __builtin_amdgcn_global_load_lds(                       \
    (const __attribute__((address_space(1))) void*)(g),                      \
    (__attribute__((address_space(3))) void*)(l), 16, 0, 0)

// fp32 -> bf16 pre-convert for x, qkv_w, proj_w (R7 version)
__global__ __launch_bounds__(256)
void convert_kernel(const float* __restrict__ x,  const float* __restrict__ qw,
                    const float* __restrict__ pw,
                    bf16_t* __restrict__ xb, bf16_t* __restrict__ qwb,
                    bf16_t* __restrict__ pwb)
{
    constexpr int NX = ROWS_ * C_;
    constexpr int NQ = QKVN_ * C_;
    constexpr int NP = C_ * C_;
    const int idx = (blockIdx.x * 256 + threadIdx.x) * 4;
    if (idx >= NX + NQ + NP) return;
    const float* src; bf16_t* dst; int off;
    if (idx < NX)           { src = x;  dst = xb;  off = idx; }
    else if (idx < NX + NQ) { src = qw; dst = qwb; off = idx - NX; }
    else                    { src = pw; dst = pwb; off = idx - NX - NQ; }
    const float4 v = *reinterpret_cast<const float4*>(src + off);
    bf16x4 o;
    o[0] = (bf16_t)v.x; o[1] = (bf16_t)v.y; o[2] = (bf16_t)v.z; o[3] = (bf16_t)v.w;
    *reinterpret_cast<bf16x4*>(dst + off) = o;
}

// C[m][n] = (sum_k A[m][k]*Wt[n][k] + bias[n]) * (n < scale_nlim ? scale : 1)
// KTILE=64, 256 threads = 4 waves. GLDS16 staging, xor-swizzled chunks.
template<int BM, int BN, int WMT, int WNT, typename OutT>
__global__ __launch_bounds__(256)
void gemm_bt(const bf16_t* __restrict__ A, const bf16_t* __restrict__ Wt,
             const float* __restrict__ bias, OutT* __restrict__ C,
             int M, int N, int K, float scale, int scale_nlim)
{
    constexpr int WCOLS = BN / (WNT * 16);
    __shared__ bf16_t Al[BM * 64];
    __shared__ bf16_t Bl[BN * 64];

    const int tid  = threadIdx.x;
    const int wave = tid >> 6;
    const int lane = tid & 63;
    const int bm = blockIdx.y * BM;
    const int bn = blockIdx.x * BN;
    const int wm = (wave / WCOLS) * (WMT * 16);
    const int wn = (wave % WCOLS) * (WNT * 16);
    const int n15 = lane & 15, q4 = lane >> 4, x7 = lane & 7;
    const int srow = lane >> 3, schunk = lane & 7;

    f32x4 acc[WMT][WNT] = {};

    for (int k0 = 0; k0 < K; k0 += 64) {
        __syncthreads();
        #pragma unroll
        for (int i = wave; i < BM / 8; i += 4) {
            const int row = i * 8 + srow;
            const int cg = schunk ^ (row & 7);
            GLDS16(A + (size_t)(bm + row) * K + k0 + cg * 8, Al + i * 512);
        }
        #pragma unroll
        for (int i = wave; i < BN / 8; i += 4) {
            const int row = i * 8 + srow;
            const int cg = schunk ^ (row & 7);
            GLDS16(Wt + (size_t)(bn + row) * K + k0 + cg * 8, Bl + i * 512);
        }
        __syncthreads();

        #pragma unroll
        for (int ks = 0; ks < 2; ++ks) {
            const int cl = (ks * 4 + q4) ^ x7;
            bf16x8 a[WMT], b[WNT];
            #pragma unroll
            for (int it = 0; it < WMT; ++it)
                a[it] = *reinterpret_cast<const bf16x8*>(
                    Al + (wm + it * 16 + n15) * 64 + cl * 8);
            #pragma unroll
            for (int jt = 0; jt < WNT; ++jt)
                b[jt] = *reinterpret_cast<const bf16x8*>(
                    Bl + (wn + jt * 16 + n15) * 64 + cl * 8);
            #pragma unroll
            for (int it = 0; it < WMT; ++it)
                #pragma unroll
                for (int jt = 0; jt < WNT; ++jt)
                    acc[it][jt] = __builtin_amdgcn_mfma_f32_16x16x32_bf16(
                        a[it], b[jt], acc[it][jt], 0, 0, 0);
        }
    }

    #pragma unroll
    for (int jt = 0; jt < WNT; ++jt) {
        const int col = bn + wn + jt * 16 + n15;
        const float bv = bias[col];
        const float sc = (col < scale_nlim) ? scale : 1.0f;
        #pragma unroll
        for (int it = 0; it < WMT; ++it) {
            const int row0 = bm + wm + it * 16 + q4 * 4;
            #pragma unroll
            for (int r = 0; r < 4; ++r)
                C[(size_t)(row0 + r) * N + col] = (OutT)((acc[it][jt][r] + bv) * sc);
        }
    }
}

// ---------------- MFMA neighborhood attention ----------------
// R7 structure + staged-split: barrier-1 drains only Q+K; V DMA issued after
// barrier-1 so its L2 fetch overlaps the S/softmax phase (drained by barrier-2,
// which exists anyway for the Kl->P alias).
static constexpr int WROW = 224;
static constexpr int PST  = 232;
static constexpr int R1B  = 64 * PST * 2;    // 29696: P region (Kl aliases)
static constexpr int R2B  = WROW * 64 * 2;   // 28672: Vl

__global__ __launch_bounds__(256)
void attn_mfma_kernel(const bf16_t* __restrict__ qkv, bf16_t* __restrict__ attn_out)
{
    int bid = blockIdx.x;
    const int h  = bid & 7;   bid >>= 3;
    const int tj = bid % 6;   bid /= 6;
    const int ti = bid % 6;   bid /= 6;
    const int b  = bid;

    const int tid = threadIdx.x;
    const int wave = tid >> 6;
    const int lane = tid & 63;
    const int n15 = lane & 15, q4 = lane >> 4, x7 = lane & 7;

    const int gi0 = ti * 8, gj0 = tj * 8;
    const int si0 = min(max(gi0 - 3, 0), H_ - 14);
    const int sj0 = min(max(gj0 - 3, 0), W_ - 14);

    __shared__ char smem[R1B + R2B];
    bf16_t* Kl = (bf16_t*)smem;
    bf16_t* P  = (bf16_t*)smem;
    bf16_t* Vl = (bf16_t*)(smem + R1B);

    // ---- Q sync loads first ----
    const int pixq = wave * 16 + n15;
    const int gpq = (b * H_ + gi0 + (pixq >> 3)) * W_ + gj0 + (pixq & 7);
    bf16x8 aq[2];
    #pragma unroll
    for (int ks = 0; ks < 2; ++ks)
        aq[ks] = *reinterpret_cast<const bf16x8*>(
            qkv + (size_t)gpq * QKVN_ + h * HD_ + ks * 32 + q4 * 8);

    // ---- K DMA only ----
    for (int i = wave; i < WROW / 8; i += 4) {
        const int row = i * 8 + (lane >> 3);
        const int wr = row >> 4;
        const int wc = min(row & 15, 13);
        const int gp = (b * H_ + si0 + wr) * W_ + sj0 + wc;
        const int cgk = (lane & 7) ^ (row & 7);
        GLDS16(qkv + (size_t)gp * QKVN_ + C_ + h * HD_ + cgk * 8, Kl + i * 512);
    }

    __syncthreads();   // drains Q + K only (V not yet issued)

    // ---- V DMA: overlaps S + softmax, drained by barrier-2 ----
    for (int i = wave; i < WROW / 8; i += 4) {
        const int row = i * 8 + (lane >> 3);
        const int wr = row >> 4;
        const int wc = min(row & 15, 13);
        const int gp = (b * H_ + si0 + wr) * W_ + sj0 + wc;
        const int cgv = (lane & 7) ^ ((row + (row >> 3)) & 7);
        GLDS16(qkv + (size_t)gp * QKVN_ + 2 * C_ + h * HD_ + cgv * 8, Vl + i * 512);
    }

    // ---- S = Q.K^T : 14 n-tiles x 2 k-steps ----
    f32x4 S[14] = {};
    #pragma unroll
    for (int j = 0; j < 14; ++j) {
        #pragma unroll
        for (int ks = 0; ks < 2; ++ks) {
            const int cl = (ks * 4 + q4) ^ x7;
            const bf16x8 bk = *reinterpret_cast<const bf16x8*>(
                Kl + (j * 16 + n15) * 64 + cl * 8);
            S[j] = __builtin_amdgcn_mfma_f32_16x16x32_bf16(aq[ks], bk, S[j], 0, 0, 0);
        }
    }

    // ---- mask: tile j = window row, n15 = window col ----
    int ri[4], cj[4];
    #pragma unroll
    for (int r = 0; r < 4; ++r) {
        const int pix = wave * 16 + q4 * 4 + r;
        const int gi = gi0 + (pix >> 3), gj = gj0 + (pix & 7);
        ri[r] = min(max(gi - 3, 0), H_ - KW_) - si0;
        cj[r] = min(max(gj - 3, 0), W_ - KW_) - sj0;
    }
    #pragma unroll
    for (int j = 0; j < 14; ++j)
        #pragma unroll
        for (int r = 0; r < 4; ++r) {
            const bool valid = ((unsigned)(j - ri[r]) < 7u) &&
                               ((unsigned)(n15 - cj[r]) < 7u);
            S[j][r] = valid ? S[j][r] : -1e30f;
        }

    // ---- softmax, no max pass (|logit| bounded; expf(-1e30) = 0) ----
    #pragma unroll
    for (int j = 0; j < 14; ++j)
        #pragma unroll
        for (int r = 0; r < 4; ++r)
            S[j][r] = __expf(S[j][r]);
    float rinv[4];
    #pragma unroll
    for (int r = 0; r < 4; ++r) {
        float s = S[0][r];
        #pragma unroll
        for (int j = 1; j < 14; ++j) s += S[j][r];
        #pragma unroll
        for (int off = 1; off < 16; off <<= 1) s += __shfl_xor(s, off);
        rinv[r] = 1.0f / s;
    }

    __syncthreads();   // Kl reads done -> safe to overwrite with P; V drained

    // ---- write P (normalized probs; masked slots exactly 0) ----
    #pragma unroll
    for (int j = 0; j < 14; ++j)
        #pragma unroll
        for (int r = 0; r < 4; ++r)
            P[(wave * 16 + q4 * 4 + r) * PST + j * 16 + n15] =
                (bf16_t)(S[j][r] * rinv[r]);

    __syncthreads();

    // ---- O^T = V^T.P^T : A gathered from natural-layout Vl ----
    const int Xv   = wave * 2 + (n15 >> 3);
    const int dlow = n15 & 7;
    f32x4 O[4] = {};
    #pragma unroll
    for (int ks = 0; ks < 7; ++ks) {
        bf16x8 av;
        #pragma unroll
        for (int u = 0; u < 8; ++u) {
            const int w = ks * 32 + q4 * 8 + u;
            const int slot = Xv ^ ((w + (w >> 3)) & 7);
            av[u] = Vl[w * 64 + slot * 8 + dlow];
        }
        #pragma unroll
        for (int j2 = 0; j2 < 4; ++j2) {
            const bf16x8 bp = *reinterpret_cast<const bf16x8*>(
                P + (j2 * 16 + n15) * PST + ks * 32 + q4 * 8);
            O[j2] = __builtin_amdgcn_mfma_f32_16x16x32_bf16(av, bp, O[j2], 0, 0, 0);
        }
    }

    // ---- epilogue ----
    #pragma unroll
    for (int j2 = 0; j2 < 4; ++j2) {
        const int pix = j2 * 16 + n15;
        const int grow = (b * H_ + gi0 + (pix >> 3)) * W_ + gj0 + (pix & 7);
        const int d0 = wave * 16 + q4 * 4;
        bf16x4 o;
        #pragma unroll
        for (int r = 0; r < 4; ++r) o[r] = (bf16_t)(O[j2][r]);
        *reinterpret_cast<bf16x4*>(attn_out + (size_t)grow * C_ + h * HD_ + d0) = o;
    }
}

extern "C" void kernel_launch(void* const* d_in, const int* in_sizes, int n_in,
                              void* d_out, int out_size, void* d_ws, size_t ws_size,
                              hipStream_t stream)
{
    const float* x      = (const float*)d_in[0];
    const float* qkv_w  = (const float*)d_in[1];
    const float* qkv_b  = (const float*)d_in[2];
    const float* proj_w = (const float*)d_in[3];
    const float* proj_b = (const float*)d_in[4];
    float* out = (float*)d_out;

    char* w = (char*)d_ws;
    bf16_t* xb    = (bf16_t*)w;  w += (size_t)ROWS_ * C_ * 2;
    bf16_t* qwb   = (bf16_t*)w;  w += (size_t)QKVN_ * C_ * 2;
    bf16_t* pwb   = (bf16_t*)w;  w += (size_t)C_ * C_ * 2;
    bf16_t* qkvb  = (bf16_t*)w;  w += (size_t)ROWS_ * QKVN_ * 2;
    bf16_t* attnb = (bf16_t*)w;

    // 0) fp32 -> bf16 casts (x + both weights)
    constexpr int TOT4 = (ROWS_ * C_ + QKVN_ * C_ + C_ * C_) / 4;
    convert_kernel<<<(TOT4 + 255) / 256, 256, 0, stream>>>(x, qkv_w, proj_w, xb, qwb, pwb);

    // 1) QKV = x @ qkv_w.T + qkv_b ; 128x64 -> 864 blocks (R7 config)
    gemm_bt<128, 64, 4, 2, bf16_t><<<dim3(QKVN_ / 64, ROWS_ / 128), 256, 0, stream>>>(
        xb, qwb, qkv_b, qkvb, ROWS_, QKVN_, C_, 0.125f, C_);

    // 2) neighborhood attention (MFMA), 576 blocks, staged-split V
    attn_mfma_kernel<<<dim3(B_ * 6 * 6 * NH_), 256, 0, stream>>>(qkvb, attnb);

    // 3) out = attn @ proj_w.T + proj_b.  128x64 -> 288 blocks (was 64x64/576)
    gemm_bt<128, 64, 4, 2, float><<<dim3(C_ / 64, ROWS_ / 128), 256, 0, stream>>>(
        attnb, pwb, proj_b, out, ROWS_, C_, C_, 1.0f, 0);
}

// Round 11
// 106.788 us; speedup vs baseline: 1.3569x; 1.0257x over previous
//
#include <hip/hip_runtime.h>

typedef __bf16 bf16_t;
typedef __bf16 bf16x8 __attribute__((ext_vector_type(8)));
typedef __bf16 bf16x4 __attribute__((ext_vector_type(4)));
typedef float  f32x4  __attribute__((ext_vector_type(4)));

static constexpr int B_   = 2;
static constexpr int H_   = 48;
static constexpr int W_   = 48;
static constexpr int C_   = 512;
static constexpr int NH_  = 8;
static constexpr int HD_  = 64;
static constexpr int KW_  = 7;
static constexpr int ROWS_ = B_ * H_ * W_;    // 4608
static constexpr int QKVN_ = 3 * C_;          // 1536

// async global->LDS, 16B per lane; LDS dest = wave-uniform base + lane*16
#define GLDS16(g, l) __builtin_amdgcn_global_load_lds(                       \
    (const __attribute__((address_space(1))) void*)(g),                      \
    (__attribute__((address_space(3))) void*)(l), 16, 0, 0)

// fp32 -> bf16 pre-convert for x, qkv_w, proj_w (R7 version)
__global__ __launch_bounds__(256)
void convert_kernel(const float* __restrict__ x,  const float* __restrict__ qw,
                    const float* __restrict__ pw,
                    bf16_t* __restrict__ xb, bf16_t* __restrict__ qwb,
                    bf16_t* __restrict__ pwb)
{
    constexpr int NX = ROWS_ * C_;
    constexpr int NQ = QKVN_ * C_;
    constexpr int NP = C_ * C_;
    const int idx = (blockIdx.x * 256 + threadIdx.x) * 4;
    if (idx >= NX + NQ + NP) return;
    const float* src; bf16_t* dst; int off;
    if (idx < NX)           { src = x;  dst = xb;  off = idx; }
    else if (idx < NX + NQ) { src = qw; dst = qwb; off = idx - NX; }
    else                    { src = pw; dst = pwb; off = idx - NX - NQ; }
    const float4 v = *reinterpret_cast<const float4*>(src + off);
    bf16x4 o;
    o[0] = (bf16_t)v.x; o[1] = (bf16_t)v.y; o[2] = (bf16_t)v.z; o[3] = (bf16_t)v.w;
    *reinterpret_cast<bf16x4*>(dst + off) = o;
}

// C[m][n] = (sum_k A[m][k]*Wt[n][k] + bias[n]) * (n < scale_nlim ? scale : 1)
// KTILE=64, 256 threads = 4 waves. GLDS16 staging, xor-swizzled chunks.
template<int BM, int BN, int WMT, int WNT, typename OutT>
__global__ __launch_bounds__(256)
void gemm_bt(const bf16_t* __restrict__ A, const bf16_t* __restrict__ Wt,
             const float* __restrict__ bias, OutT* __restrict__ C,
             int M, int N, int K, float scale, int scale_nlim)
{
    constexpr int WCOLS = BN / (WNT * 16);
    __shared__ bf16_t Al[BM * 64];
    __shared__ bf16_t Bl[BN * 64];

    const int tid  = threadIdx.x;
    const int wave = tid >> 6;
    const int lane = tid & 63;
    const int bm = blockIdx.y * BM;
    const int bn = blockIdx.x * BN;
    const int wm = (wave / WCOLS) * (WMT * 16);
    const int wn = (wave % WCOLS) * (WNT * 16);
    const int n15 = lane & 15, q4 = lane >> 4, x7 = lane & 7;
    const int srow = lane >> 3, schunk = lane & 7;

    f32x4 acc[WMT][WNT] = {};

    for (int k0 = 0; k0 < K; k0 += 64) {
        __syncthreads();
        #pragma unroll
        for (int i = wave; i < BM / 8; i += 4) {
            const int row = i * 8 + srow;
            const int cg = schunk ^ (row & 7);
            GLDS16(A + (size_t)(bm + row) * K + k0 + cg * 8, Al + i * 512);
        }
        #pragma unroll
        for (int i = wave; i < BN / 8; i += 4) {
            const int row = i * 8 + srow;
            const int cg = schunk ^ (row & 7);
            GLDS16(Wt + (size_t)(bn + row) * K + k0 + cg * 8, Bl + i * 512);
        }
        __syncthreads();

        #pragma unroll
        for (int ks = 0; ks < 2; ++ks) {
            const int cl = (ks * 4 + q4) ^ x7;
            bf16x8 a[WMT], b[WNT];
            #pragma unroll
            for (int it = 0; it < WMT; ++it)
                a[it] = *reinterpret_cast<const bf16x8*>(
                    Al + (wm + it * 16 + n15) * 64 + cl * 8);
            #pragma unroll
            for (int jt = 0; jt < WNT; ++jt)
                b[jt] = *reinterpret_cast<const bf16x8*>(
                    Bl + (wn + jt * 16 + n15) * 64 + cl * 8);
            #pragma unroll
            for (int it = 0; it < WMT; ++it)
                #pragma unroll
                for (int jt = 0; jt < WNT; ++jt)
                    acc[it][jt] = __builtin_amdgcn_mfma_f32_16x16x32_bf16(
                        a[it], b[jt], acc[it][jt], 0, 0, 0);
        }
    }

    #pragma unroll
    for (int jt = 0; jt < WNT; ++jt) {
        const int col = bn + wn + jt * 16 + n15;
        const float bv = bias[col];
        const float sc = (col < scale_nlim) ? scale : 1.0f;
        #pragma unroll
        for (int it = 0; it < WMT; ++it) {
            const int row0 = bm + wm + it * 16 + q4 * 4;
            #pragma unroll
            for (int r = 0; r < 4; ++r)
                C[(size_t)(row0 + r) * N + col] = (OutT)((acc[it][jt][r] + bv) * sc);
        }
    }
}

// ---------------- MFMA neighborhood attention ----------------
// v3: no V LDS buffer at all. LDS = 29.7 KB (K tile, aliased by P) ->
// 4-5 blocks/CU instead of 2. PV A-fragments (V[w][d], d lane-resident)
// are gathered straight from global: w&15 is ks-invariant, so 8 per-u base
// pointers + uniform ks*2*W*QKVN element offset cover all 56 loads; they
// issue before the P-write barriers, which hide their L2 latency.
static constexpr int WROW = 224;
static constexpr int PST  = 232;
static constexpr int R1B  = 64 * PST * 2;    // 29696: P region (Kl aliases)

__global__ __launch_bounds__(256)
void attn_mfma_kernel(const bf16_t* __restrict__ qkv, bf16_t* __restrict__ attn_out)
{
    int bid = blockIdx.x;
    const int h  = bid & 7;   bid >>= 3;
    const int tj = bid % 6;   bid /= 6;
    const int ti = bid % 6;   bid /= 6;
    const int b  = bid;

    const int tid = threadIdx.x;
    const int wave = tid >> 6;
    const int lane = tid & 63;
    const int n15 = lane & 15, q4 = lane >> 4, x7 = lane & 7;

    const int gi0 = ti * 8, gj0 = tj * 8;
    const int si0 = min(max(gi0 - 3, 0), H_ - 14);
    const int sj0 = min(max(gj0 - 3, 0), W_ - 14);

    __shared__ char smem[R1B];
    bf16_t* Kl = (bf16_t*)smem;            // [224][64] swizzled
    bf16_t* P  = (bf16_t*)smem;            // [64][232], aliases Kl

    // ---- Q sync loads ----
    const int pixq = wave * 16 + n15;
    const int gpq = (b * H_ + gi0 + (pixq >> 3)) * W_ + gj0 + (pixq & 7);
    bf16x8 aq[2];
    #pragma unroll
    for (int ks = 0; ks < 2; ++ks)
        aq[ks] = *reinterpret_cast<const bf16x8*>(
            qkv + (size_t)gpq * QKVN_ + h * HD_ + ks * 32 + q4 * 8);

    // ---- K DMA ----
    for (int i = wave; i < WROW / 8; i += 4) {
        const int row = i * 8 + (lane >> 3);
        const int wr = row >> 4;
        const int wc = min(row & 15, 13);
        const int gp = (b * H_ + si0 + wr) * W_ + sj0 + wc;
        const int cgk = (lane & 7) ^ (row & 7);
        GLDS16(qkv + (size_t)gp * QKVN_ + C_ + h * HD_ + cgk * 8, Kl + i * 512);
    }

    __syncthreads();   // drains Q + K

    // ---- S = Q.K^T : 14 n-tiles x 2 k-steps ----
    f32x4 S[14] = {};
    #pragma unroll
    for (int j = 0; j < 14; ++j) {
        #pragma unroll
        for (int ks = 0; ks < 2; ++ks) {
            const int cl = (ks * 4 + q4) ^ x7;
            const bf16x8 bk = *reinterpret_cast<const bf16x8*>(
                Kl + (j * 16 + n15) * 64 + cl * 8);
            S[j] = __builtin_amdgcn_mfma_f32_16x16x32_bf16(aq[ks], bk, S[j], 0, 0, 0);
        }
    }

    // ---- V gather from global (independent of LDS; latency hidden by
    //      softmax + barriers below). av_all[ks] = V[w=ks*32+q4*8+u][d] ----
    const int d = wave * 16 + n15;
    bf16x8 av_all[7];
    {
        const int base0 = (b * H_ + si0) * W_ + sj0;
        #pragma unroll
        for (int u = 0; u < 8; ++u) {
            const int w0 = q4 * 8 + u;               // w&31 part; w>>4 adds 2/ks
            const int wr0 = w0 >> 4;
            const int wc0 = min(w0 & 15, 13);
            const bf16_t* p0 = qkv + (size_t)(base0 + wr0 * W_ + wc0) * QKVN_
                                   + 2 * C_ + h * HD_ + d;
            #pragma unroll
            for (int ks = 0; ks < 7; ++ks)
                av_all[ks][u] = p0[(size_t)ks * 2 * W_ * QKVN_];
        }
    }

    // ---- mask: tile j = window row, n15 = window col ----
    int ri[4], cj[4];
    #pragma unroll
    for (int r = 0; r < 4; ++r) {
        const int pix = wave * 16 + q4 * 4 + r;
        const int gi = gi0 + (pix >> 3), gj = gj0 + (pix & 7);
        ri[r] = min(max(gi - 3, 0), H_ - KW_) - si0;
        cj[r] = min(max(gj - 3, 0), W_ - KW_) - sj0;
    }
    #pragma unroll
    for (int j = 0; j < 14; ++j)
        #pragma unroll
        for (int r = 0; r < 4; ++r) {
            const bool valid = ((unsigned)(j - ri[r]) < 7u) &&
                               ((unsigned)(n15 - cj[r]) < 7u);
            S[j][r] = valid ? S[j][r] : -1e30f;
        }

    // ---- softmax, no max pass (|logit| bounded; expf(-1e30) = 0) ----
    #pragma unroll
    for (int j = 0; j < 14; ++j)
        #pragma unroll
        for (int r = 0; r < 4; ++r)
            S[j][r] = __expf(S[j][r]);
    float rinv[4];
    #pragma unroll
    for (int r = 0; r < 4; ++r) {
        float s = S[0][r];
        #pragma unroll
        for (int j = 1; j < 14; ++j) s += S[j][r];
        #pragma unroll
        for (int off = 1; off < 16; off <<= 1) s += __shfl_xor(s, off);
        rinv[r] = 1.0f / s;
    }

    __syncthreads();   // Kl reads done -> safe to overwrite with P

    // ---- write P (normalized probs; masked slots exactly 0) ----
    #pragma unroll
    for (int j = 0; j < 14; ++j)
        #pragma unroll
        for (int r = 0; r < 4; ++r)
            P[(wave * 16 + q4 * 4 + r) * PST + j * 16 + n15] =
                (bf16_t)(S[j][r] * rinv[r]);

    __syncthreads();

    // ---- O^T = V^T.P^T : A from registers (av_all), B from P ----
    f32x4 O[4] = {};
    #pragma unroll
    for (int ks = 0; ks < 7; ++ks) {
        #pragma unroll
        for (int j2 = 0; j2 < 4; ++j2) {
            const bf16x8 bp = *reinterpret_cast<const bf16x8*>(
                P + (j2 * 16 + n15) * PST + ks * 32 + q4 * 8);
            O[j2] = __builtin_amdgcn_mfma_f32_16x16x32_bf16(av_all[ks], bp, O[j2], 0, 0, 0);
        }
    }

    // ---- epilogue: D[m=d][n=pix] ----
    #pragma unroll
    for (int j2 = 0; j2 < 4; ++j2) {
        const int pix = j2 * 16 + n15;
        const int grow = (b * H_ + gi0 + (pix >> 3)) * W_ + gj0 + (pix & 7);
        const int d0 = wave * 16 + q4 * 4;
        bf16x4 o;
        #pragma unroll
        for (int r = 0; r < 4; ++r) o[r] = (bf16_t)(O[j2][r]);
        *reinterpret_cast<bf16x4*>(attn_out + (size_t)grow * C_ + h * HD_ + d0) = o;
    }
}

extern "C" void kernel_launch(void* const* d_in, const int* in_sizes, int n_in,
                              void* d_out, int out_size, void* d_ws, size_t ws_size,
                              hipStream_t stream)
{
    const float* x      = (const float*)d_in[0];
    const float* qkv_w  = (const float*)d_in[1];
    const float* qkv_b  = (const float*)d_in[2];
    const float* proj_w = (const float*)d_in[3];
    const float* proj_b = (const float*)d_in[4];
    float* out = (float*)d_out;

    char* w = (char*)d_ws;
    bf16_t* xb    = (bf16_t*)w;  w += (size_t)ROWS_ * C_ * 2;
    bf16_t* qwb   = (bf16_t*)w;  w += (size_t)QKVN_ * C_ * 2;
    bf16_t* pwb   = (bf16_t*)w;  w += (size_t)C_ * C_ * 2;
    bf16_t* qkvb  = (bf16_t*)w;  w += (size_t)ROWS_ * QKVN_ * 2;
    bf16_t* attnb = (bf16_t*)w;

    // 0) fp32 -> bf16 casts (x + both weights)
    constexpr int TOT4 = (ROWS_ * C_ + QKVN_ * C_ + C_ * C_) / 4;
    convert_kernel<<<(TOT4 + 255) / 256, 256, 0, stream>>>(x, qkv_w, proj_w, xb, qwb, pwb);

    // 1) QKV = x @ qkv_w.T + qkv_b ; 128x64 -> 864 blocks (R7 config)
    gemm_bt<128, 64, 4, 2, bf16_t><<<dim3(QKVN_ / 64, ROWS_ / 128), 256, 0, stream>>>(
        xb, qwb, qkv_b, qkvb, ROWS_, QKVN_, C_, 0.125f, C_);

    // 2) neighborhood attention (MFMA), 576 blocks, LDS 29.7 KB (4-5 blk/CU)
    attn_mfma_kernel<<<dim3(B_ * 6 * 6 * NH_), 256, 0, stream>>>(qkvb, attnb);

    // 3) out = attn @ proj_w.T + proj_b.  64x64 -> 576 blocks (measured best)
    gemm_bt<64, 64, 2, 2, float><<<dim3(C_ / 64, ROWS_ / 64), 256, 0, stream>>>(
        attnb, pwb, proj_b, out, ROWS_, C_, C_, 1.0f, 0);
}